// Round 7
// baseline (100.662 us; speedup 1.0000x reference)
//
#include <hip/hip_runtime.h>

// Chamfer distance via bf16 MFMA with hi/lo split (fp32-grade precision).
// d(p,q) = ||p||^2 + ||q||^2 - 2 p.q.
// A row (target): [uh x3, uh x3, ul x3, ul x3, wh wm wl, 0], u=-2t, w=||t||^2
// B col (query):  [qh x3, ql x3, qh x3, ql x3, 1 1 1, 0]
// => D = -2 t.q + ||t||^2 + O(1e-5); query ||q||^2 added after the min.
// Round-6-proven data path; nn now 512 threads / 8 waves per block, each wave
// one 32-query B-set (1 ds_read + 1 MFMA + 8 min3 per tile) -> 4 waves/SIMD
// for MFMA latency hiding. 3 graph nodes total.

typedef short bf16x8 __attribute__((ext_vector_type(8)));
typedef float f32x16 __attribute__((ext_vector_type(16)));

#define B_SZ   8
#define NPTS   8192
#define TOTAL  (B_SZ * NPTS)     // 65536
#define BLOCK  256               // prep block
#define NNB    512               // nn block: 8 waves
#define QB     256               // queries per block
#define SLICE  1024              // targets per LDS stage
#define NSTAGE (NPTS / SLICE)    // 8
#define TILES  (SLICE / 32)      // 32

// round-to-nearest bf16 (half-up via +0x8000 carry), return remainder
__device__ __forceinline__ unsigned short bf16rn(float f, float* rem) {
    unsigned u = __float_as_uint(f);
    unsigned h = (u + 0x8000u) & 0xFFFF0000u;
    *rem = f - __uint_as_float(h);
    return (unsigned short)(h >> 16);
}

// One thread per point; blockIdx.y: 0 = gt, 1 = pred.  (round-4/6 exact)
__global__ __launch_bounds__(BLOCK) void chamfer_prep_mfma(
    const float* __restrict__ gt, const float* __restrict__ pred,
    uint4* __restrict__ TgA, uint4* __restrict__ TgB, float* __restrict__ Wg,
    uint4* __restrict__ TpA, uint4* __restrict__ TpB, float* __restrict__ Wp)
{
    int i = blockIdx.x * BLOCK + threadIdx.x;
    const float* src = blockIdx.y ? pred : gt;
    uint4* TA = blockIdx.y ? TpA : TgA;
    uint4* TB = blockIdx.y ? TpB : TgB;
    float* W  = blockIdx.y ? Wp  : Wg;

    float x = src[3 * (size_t)i + 0];
    float y = src[3 * (size_t)i + 1];
    float z = src[3 * (size_t)i + 2];
    float w = fmaf(x, x, fmaf(y, y, z * z));
    W[i] = w;

    float ux = -2.f * x, uy = -2.f * y, uz = -2.f * z;
    float rx, ry, rz, dx, dy, dz, rw1, rw2, rw3;
    unsigned short uhx = bf16rn(ux, &rx), uhy = bf16rn(uy, &ry), uhz = bf16rn(uz, &rz);
    unsigned short ulx = bf16rn(rx, &dx), uly = bf16rn(ry, &dy), ulz = bf16rn(rz, &dz);
    unsigned short wh = bf16rn(w, &rw1), wm = bf16rn(rw1, &rw2), wl = bf16rn(rw2, &rw3);
    union { unsigned short s[16]; uint4 v[2]; } A;
    A.s[0] = uhx; A.s[1] = uhy; A.s[2]  = uhz;
    A.s[3] = uhx; A.s[4] = uhy; A.s[5]  = uhz;
    A.s[6] = ulx; A.s[7] = uly; A.s[8]  = ulz;
    A.s[9] = ulx; A.s[10] = uly; A.s[11] = ulz;
    A.s[12] = wh; A.s[13] = wm; A.s[14] = wl; A.s[15] = 0;
    TA[2 * (size_t)i]     = A.v[0];
    TA[2 * (size_t)i + 1] = A.v[1];

    float sx, sy, sz, ex, ey, ez;
    unsigned short qhx = bf16rn(x, &sx), qhy = bf16rn(y, &sy), qhz = bf16rn(z, &sz);
    unsigned short qlx = bf16rn(sx, &ex), qly = bf16rn(sy, &ey), qlz = bf16rn(sz, &ez);
    union { unsigned short s[16]; uint4 v[2]; } Bb;
    Bb.s[0] = qhx; Bb.s[1] = qhy; Bb.s[2]  = qhz;
    Bb.s[3] = qlx; Bb.s[4] = qly; Bb.s[5]  = qlz;
    Bb.s[6] = qhx; Bb.s[7] = qhy; Bb.s[8]  = qhz;
    Bb.s[9] = qlx; Bb.s[10] = qly; Bb.s[11] = qlz;
    Bb.s[12] = 0x3F80; Bb.s[13] = 0x3F80; Bb.s[14] = 0x3F80; Bb.s[15] = 0;
    TB[2 * (size_t)i]     = Bb.v[0];
    TB[2 * (size_t)i + 1] = Bb.v[1];
}

// m = min(m, d[0..15]) : min3-fusable triples (8 x v_min3_f32 when fused)
__device__ __forceinline__ float minred(f32x16 d, float m) {
    float r0 = fminf(fminf(d[0], d[1]), d[2]);
    float r1 = fminf(fminf(d[3], d[4]), d[5]);
    float r2 = fminf(fminf(d[6], d[7]), d[8]);
    float r3 = fminf(fminf(d[9], d[10]), d[11]);
    float r4 = fminf(fminf(d[12], d[13]), d[14]);
    float s0 = fminf(fminf(r0, r1), r2);
    float s1 = fminf(fminf(r3, r4), d[15]);
    return fminf(fminf(m, s0), s1);
}

// grid (NPTS/QB=32, B_SZ=8, 2 dirs), 512 threads / 8 waves.
// Wave w covers queries qb*256 + w*32 .. +31 (one B-set). All 8192 targets
// via 8 LDS stages. One atomicAdd per block.
__global__ __launch_bounds__(NNB, 4) void chamfer_nn_fused(
    const uint4* __restrict__ TgA, const uint4* __restrict__ TpB,
    const float* __restrict__ Wp,
    const uint4* __restrict__ TpA, const uint4* __restrict__ TgB,
    const float* __restrict__ Wg,
    float* __restrict__ out)
{
    __shared__ uint4 tileU[SLICE * 2];       // 32 KiB A-forms
    __shared__ float psum[8];
    char* tileC = (char*)tileU;

    const int qb = blockIdx.x, b = blockIdx.y, dir = blockIdx.z;
    const int t = threadIdx.x, lane = t & 63, wid = t >> 6;
    const int col = lane & 31, hi = lane >> 5;

    const uint4* TA = dir ? TpA : TgA;
    const uint4* TB = dir ? TgB : TpB;
    const float* WQ = dir ? Wg  : Wp;

    // B fragment from global (round-4/6 exact addressing): this wave's 32 queries
    const int qblk = qb * QB + wid * 32;
    const char* TBc = (const char*)(TB + ((size_t)b * NPTS + qblk) * 2);
    bf16x8 bq0 = *(const bf16x8*)(TBc + (size_t)col * 32 + hi * 16);

    f32x16 zacc;
#pragma unroll
    for (int j = 0; j < 16; ++j) zacc[j] = 0.f;
    float m0 = 3.0e38f;
    // swizzled A-frag base; per-tile offset is the imm tt*1024
    const int abase = (col * 32 + hi * 16) ^ (((col >> 2) & 7) << 4);

    for (int st = 0; st < NSTAGE; ++st) {
        // stage SLICE targets: granule-swizzled copy (round-4/6 exact),
        // 2048 granules by 512 threads = 4 each
        const uint4* srcA = TA + ((size_t)b * NPTS + (size_t)st * SLICE) * 2;
#pragma unroll
        for (int it = 0; it < (SLICE * 2) / NNB; ++it) {
            int g = t + it * NNB;
            uint4 v = srcA[g];
            int tl = g >> 1, gh = g & 1;
            int off = (tl * 32 + gh * 16) ^ (((tl >> 2) & 7) << 4);
            *(uint4*)(tileC + off) = v;
        }
        __syncthreads();

#pragma unroll 2
        for (int tt = 0; tt < TILES; ++tt) {
            bf16x8 a = *(const bf16x8*)(tileC + abase + tt * 1024);
            f32x16 d0 = __builtin_amdgcn_mfma_f32_32x32x16_bf16(a, bq0, zacc, 0, 0, 0);
            m0 = minred(d0, m0);
        }
        __syncthreads();
    }

    // epilogue: combine row-halves (lanes l, l^32 share query col), add ||q||^2
    m0 = fminf(m0, __shfl_xor(m0, 32));
    // lanes 0..31 hold query qblk+col; lanes >=32 duplicate -> contribute 0
    float s = 0.0f;
    if (lane < 32) {
        float wq = WQ[(size_t)b * NPTS + qblk + col];
        s = fmaxf(m0 + wq, 0.0f);
    }
#pragma unroll
    for (int o = 1; o < 64; o <<= 1) s += __shfl_xor(s, o);
    if (lane == 0) psum[wid] = s;
    __syncthreads();
    if (t == 0) {
        float tot = ((psum[0] + psum[1]) + (psum[2] + psum[3]))
                  + ((psum[4] + psum[5]) + (psum[6] + psum[7]));
        atomicAdd(out, tot * (1.0f / (float)TOTAL));
    }
}

extern "C" void kernel_launch(void* const* d_in, const int* in_sizes, int n_in,
                              void* d_out, int out_size, void* d_ws, size_t ws_size,
                              hipStream_t stream) {
    const float* pred = (const float*)d_in[0];   // [B, N, 3]
    const float* gt   = (const float*)d_in[1];   // [B, M, 3]
    float* out = (float*)d_out;

    // ws layout: TgA, TpA, TgB, TpB (32B/point), Wg, Wp
    char* ws = (char*)d_ws;
    uint4* TgA = (uint4*)(ws);
    uint4* TpA = (uint4*)(ws + (size_t)TOTAL * 32);
    uint4* TgB = (uint4*)(ws + (size_t)TOTAL * 64);
    uint4* TpB = (uint4*)(ws + (size_t)TOTAL * 96);
    float* Wg  = (float*)(ws + (size_t)TOTAL * 128);
    float* Wp  = (float*)(ws + (size_t)TOTAL * 128 + (size_t)TOTAL * 4);

    hipMemsetAsync(out, 0, sizeof(float), stream);

    chamfer_prep_mfma<<<dim3(TOTAL / BLOCK, 2), BLOCK, 0, stream>>>(
        gt, pred, TgA, TgB, Wg, TpA, TpB, Wp);

    chamfer_nn_fused<<<dim3(NPTS / QB, B_SZ, 2), NNB, 0, stream>>>(
        TgA, TpB, Wp, TpA, TgB, Wg, out);
}